// Round 1
// baseline (48.742 us; speedup 1.0000x reference)
//
#include <hip/hip_runtime.h>

#define IMG_W 256
#define IMG_H 256
#define NG 512
#define FOCAL 50.0f

// Preprocess + stable depth sort. One block of NG threads.
// ws layout: per sorted gaussian, 2x float4:
//   [pu, pv, a, b] with a = -0.5*log2(e)/su^2, b likewise for sv
//   [opacity, cr, cg, cb]
__global__ __launch_bounds__(NG) void prep_kernel(
    const float* __restrict__ means3d, const float* __restrict__ scales,
    const float* __restrict__ opac, const float* __restrict__ colors,
    float4* __restrict__ ws4)
{
    __shared__ float zsh[NG];
    const int i = threadIdx.x;
    const float mx = means3d[3 * i];
    const float my = means3d[3 * i + 1];
    const float mz = means3d[3 * i + 2];
    const float z = fmaxf(mz, 0.1f);
    zsh[i] = z;
    __syncthreads();

    // Stable rank: count j strictly before i in (z, index) order.
    int rank = 0;
    #pragma unroll 8
    for (int j = 0; j < NG; ++j) {
        const float zj = zsh[j];
        rank += (zj < z) || (zj == z && j < i);
    }

    const float inv_z = 1.0f / z;
    const float pu = FOCAL * mx * inv_z;
    const float pv = FOCAL * my * inv_z;
    const float su = fmaxf(FOCAL * scales[3 * i] * inv_z, 0.5f);
    const float sv = fmaxf(FOCAL * scales[3 * i + 1] * inv_z, 0.5f);
    const float c = -0.5f * 1.44269504088896340736f;  // -log2(e)/2
    const float a = c / (su * su);
    const float b = c / (sv * sv);

    ws4[2 * rank]     = make_float4(pu, pv, a, b);
    ws4[2 * rank + 1] = make_float4(opac[i], colors[3 * i], colors[3 * i + 1], colors[3 * i + 2]);
}

// One thread per pixel; composite all NG sorted gaussians front-to-back.
__global__ __launch_bounds__(256) void raster_kernel(
    const float4* __restrict__ ws4, float* __restrict__ out)
{
    __shared__ float4 g[2 * NG];
    for (int t = threadIdx.x; t < 2 * NG; t += 256) g[t] = ws4[t];
    __syncthreads();

    const int pid = blockIdx.x * 256 + threadIdx.x;
    const float u = (float)(pid & (IMG_W - 1)) - (float)(IMG_W / 2);
    const float v = (float)(pid >> 8) - (float)(IMG_H / 2);

    float T = 1.0f;
    float r = 0.0f, gch = 0.0f, bch = 0.0f;

    #pragma unroll 8
    for (int n = 0; n < NG; ++n) {
        const float4 p0 = g[2 * n];       // pu, pv, a, b   (broadcast: all lanes same addr)
        const float4 p1 = g[2 * n + 1];   // opac, r, g, b
        const float du = u - p0.x;
        const float dv = v - p0.y;
        const float arg = du * du * p0.z + dv * dv * p0.w;  // already includes -0.5*log2e
        const float gauss = exp2f(arg);                      // v_exp_f32
        const float alpha = fminf(gauss * p1.x, 1.0f);       // alpha in [0,1]
        const float w = alpha * T;
        r   += w * p1.y;
        gch += w * p1.z;
        bch += w * p1.w;
        T   -= w;  // T *= (1 - alpha)
    }

    out[3 * pid]     = r;
    out[3 * pid + 1] = gch;
    out[3 * pid + 2] = bch;
}

extern "C" void kernel_launch(void* const* d_in, const int* in_sizes, int n_in,
                              void* d_out, int out_size, void* d_ws, size_t ws_size,
                              hipStream_t stream) {
    const float* means3d = (const float*)d_in[0];
    const float* scales  = (const float*)d_in[1];
    const float* opac    = (const float*)d_in[2];
    const float* colors  = (const float*)d_in[3];
    float* out = (float*)d_out;
    float4* ws4 = (float4*)d_ws;  // needs 2*NG*16 = 16 KB

    prep_kernel<<<1, NG, 0, stream>>>(means3d, scales, opac, colors, ws4);
    raster_kernel<<<(IMG_W * IMG_H) / 256, 256, 0, stream>>>(ws4, out);
}

// Round 2
// 38.331 us; speedup vs baseline: 1.2716x; 1.2716x over previous
//
#include <hip/hip_runtime.h>

#define IMG_W 256
#define IMG_H 256
#define NG 512
#define NSEG 4
#define SEGLEN (NG / NSEG)   // 128
#define PXB 256              // pixels per block (one image row)
#define FOCAL 50.0f

// Preprocess + stable depth sort. One block of NG threads.
// ws layout: per sorted gaussian, 2x float4:
//   [pu, pv, a, b] with a = -0.5*log2(e)/su^2, b likewise for sv
//   [opacity, cr, cg, cb]
__global__ __launch_bounds__(NG) void prep_kernel(
    const float* __restrict__ means3d, const float* __restrict__ scales,
    const float* __restrict__ opac, const float* __restrict__ colors,
    float4* __restrict__ ws4)
{
    __shared__ float zsh[NG];
    const int i = threadIdx.x;
    const float mx = means3d[3 * i];
    const float my = means3d[3 * i + 1];
    const float mz = means3d[3 * i + 2];
    const float z = fmaxf(mz, 0.1f);
    zsh[i] = z;
    __syncthreads();

    // Stable rank: count j strictly before i in (z, index) order.
    int rank = 0;
    #pragma unroll 8
    for (int j = 0; j < NG; ++j) {
        const float zj = zsh[j];
        rank += (zj < z) || (zj == z && j < i);
    }

    const float inv_z = 1.0f / z;
    const float pu = FOCAL * mx * inv_z;
    const float pv = FOCAL * my * inv_z;
    const float su = fmaxf(FOCAL * scales[3 * i] * inv_z, 0.5f);
    const float sv = fmaxf(FOCAL * scales[3 * i + 1] * inv_z, 0.5f);
    const float c = -0.5f * 1.44269504088896340736f;  // -log2(e)/2
    const float a = c / (su * su);
    const float b = c / (sv * sv);

    ws4[2 * rank]     = make_float4(pu, pv, a, b);
    ws4[2 * rank + 1] = make_float4(opac[i], colors[3 * i], colors[3 * i + 1], colors[3 * i + 2]);
}

// One block per image row: 256 px x 4 depth-segments = 1024 threads (4 waves/SIMD).
// Each (px, seg) thread composites 128 sorted gaussians -> partial (rgb, T).
// Segments combined in-block via LDS: img = p0 + T0*(p1 + T1*(p2 + T2*p3)).
__global__ __launch_bounds__(1024, 1) void raster_kernel(
    const float4* __restrict__ ws4, float* __restrict__ out)
{
    __shared__ float4 g[2 * NG];                 // 16 KB gaussian table
    __shared__ float4 part[NSEG - 1][PXB];       // 12 KB partials (seg 1..3)

    const int tid = threadIdx.x;
    g[tid] = ws4[tid];                           // 1024 threads stage 1024 float4
    __syncthreads();

    const int p   = tid & (PXB - 1);
    const int seg = tid >> 8;
    const int pid = blockIdx.x * PXB + p;
    const float u = (float)(pid & (IMG_W - 1)) - (float)(IMG_W / 2);
    const float v = (float)(pid >> 8) - (float)(IMG_H / 2);

    float T = 1.0f;
    float r = 0.0f, gc = 0.0f, bc = 0.0f;

    const int base = 2 * seg * SEGLEN;
    #pragma unroll 8
    for (int n = 0; n < SEGLEN; ++n) {
        const float4 p0 = g[base + 2 * n];       // pu, pv, a, b  (uniform broadcast)
        const float4 p1 = g[base + 2 * n + 1];   // opac, r, g, b
        const float du = u - p0.x;
        const float dv = v - p0.y;
        const float arg = fmaf(du * du, p0.z, dv * dv * p0.w);  // includes -0.5*log2e
        const float alpha = p1.x * exp2f(arg);   // gauss<=1, opac<1 => alpha<=1, no clip needed
        const float w = alpha * T;
        r  = fmaf(w, p1.y, r);
        gc = fmaf(w, p1.z, gc);
        bc = fmaf(w, p1.w, bc);
        T -= w;                                   // T *= (1 - alpha)
    }

    if (seg) part[seg - 1][p] = make_float4(r, gc, bc, T);
    __syncthreads();

    if (seg == 0) {
        const float4 s1 = part[0][p];
        const float4 s2 = part[1][p];
        const float4 s3 = part[2][p];
        // back-to-front segment composition
        float cr = fmaf(s2.w, s3.x, s2.x);
        float cg = fmaf(s2.w, s3.y, s2.y);
        float cb = fmaf(s2.w, s3.z, s2.z);
        cr = fmaf(s1.w, cr, s1.x);
        cg = fmaf(s1.w, cg, s1.y);
        cb = fmaf(s1.w, cb, s1.z);
        out[3 * pid]     = fmaf(T, cr, r);
        out[3 * pid + 1] = fmaf(T, cg, gc);
        out[3 * pid + 2] = fmaf(T, cb, bc);
    }
}

extern "C" void kernel_launch(void* const* d_in, const int* in_sizes, int n_in,
                              void* d_out, int out_size, void* d_ws, size_t ws_size,
                              hipStream_t stream) {
    const float* means3d = (const float*)d_in[0];
    const float* scales  = (const float*)d_in[1];
    const float* opac    = (const float*)d_in[2];
    const float* colors  = (const float*)d_in[3];
    float* out = (float*)d_out;
    float4* ws4 = (float4*)d_ws;  // needs 2*NG*16 = 16 KB

    prep_kernel<<<1, NG, 0, stream>>>(means3d, scales, opac, colors, ws4);
    raster_kernel<<<IMG_H, 1024, 0, stream>>>(ws4, out);
}

// Round 4
// 23.891 us; speedup vs baseline: 2.0402x; 1.6044x over previous
//
#include <hip/hip_runtime.h>

#define IMG_W 256
#define IMG_H 256
#define NG 512
#define NSEG 4
#define SEGLEN (NG / NSEG)   // 128
#define PXB 256              // pixels per block (one image row)
#define FOCAL 50.0f

// Single fused kernel. One block per image row, 1024 threads.
// Phase 1 (prep): block-local stable depth sort of all NG gaussians via
//   u64 keys (zbits<<32 | idx); rank of gaussian i is split between
//   thread i (counts keys [0,256)) and thread i+512 (counts [256,512)).
// Phase 2 (raster): 256 px x 4 depth-segments; each thread composites
//   SEGLEN gaussians; segments combined back-to-front through LDS.
__global__ __launch_bounds__(1024, 1) void fused_kernel(
    const float* __restrict__ means3d, const float* __restrict__ scales,
    const float* __restrict__ opac, const float* __restrict__ colors,
    float* __restrict__ out)
{
    __shared__ __align__(16) unsigned long long zkey[NG];  // 4 KB
    __shared__ int rpart[NG];                    // 2 KB upper-half partial ranks
    __shared__ float4 g0[NG];                    // pu, pv, a, b
    __shared__ float4 g1[NG];                    // log2(opac), r, g, b
    __shared__ float4 part[NSEG - 1][PXB];       // 12 KB segment partials

    const int tid = threadIdx.x;
    const int i = tid & (NG - 1);                // gaussian id for prep (both halves)

    // ---- phase 1: keys ----
    float z = 0.0f, mx = 0.0f, my = 0.0f;
    if (tid < NG) {
        mx = means3d[3 * i];
        my = means3d[3 * i + 1];
        z  = fmaxf(means3d[3 * i + 2], 0.1f);
        zkey[i] = ((unsigned long long)__float_as_uint(z) << 32) | (unsigned)i;
    }
    __syncthreads();

    // ---- phase 1: split rank count ----
    // Every thread gets gaussian i's key from LDS (upper half never loaded z).
    const unsigned long long mykey = zkey[i];
    int cnt = 0;
    {
        const ulonglong2* kp = (const ulonglong2*)zkey + ((tid >> 9) * (NG / 4));
        #pragma unroll 8
        for (int jj = 0; jj < NG / 4; ++jj) {    // 128 iters, 2 keys per b128 read
            const ulonglong2 kk = kp[jj];
            cnt += (kk.x < mykey);
            cnt += (kk.y < mykey);
        }
    }
    if (tid >= NG) rpart[i] = cnt;               // upper half publishes [256,512) count
    __syncthreads();

    if (tid < NG) {
        const float inv_z = 1.0f / z;
        const float pu = FOCAL * mx * inv_z;
        const float pv = FOCAL * my * inv_z;
        const float su = fmaxf(FOCAL * scales[3 * i] * inv_z, 0.5f);
        const float sv = fmaxf(FOCAL * scales[3 * i + 1] * inv_z, 0.5f);
        const float c = -0.5f * 1.44269504088896340736f;  // -log2(e)/2
        const float a = c / (su * su);
        const float b = c / (sv * sv);
        const float lop = __log2f(opac[i]);
        const float cr = colors[3 * i], cg = colors[3 * i + 1], cb = colors[3 * i + 2];
        const int rank = cnt + rpart[i];         // unique: keys are distinct
        g0[rank] = make_float4(pu, pv, a, b);
        g1[rank] = make_float4(lop, cr, cg, cb);
    }
    __syncthreads();

    // ---- phase 2: raster ----
    const int p   = tid & (PXB - 1);
    const int seg = tid >> 8;
    const int pid = blockIdx.x * PXB + p;
    const float u = (float)p - (float)(IMG_W / 2);
    const float v = (float)blockIdx.x - (float)(IMG_H / 2);

    float T = 1.0f;
    float r = 0.0f, gc = 0.0f, bc = 0.0f;

    const int base = seg * SEGLEN;
    #pragma unroll 8
    for (int n = 0; n < SEGLEN; ++n) {
        const float4 p0 = g0[base + n];          // uniform broadcast reads
        const float4 p1 = g1[base + n];
        const float du = u - p0.x;
        const float dv = v - p0.y;
        const float e = fmaf(du * du, p0.z, fmaf(dv * dv, p0.w, p1.x)); // + log2(opac)
        const float alpha = __builtin_amdgcn_exp2f(e);   // v_exp_f32; alpha <= opac < 1
        const float w = alpha * T;
        r  = fmaf(w, p1.y, r);
        gc = fmaf(w, p1.z, gc);
        bc = fmaf(w, p1.w, bc);
        T -= w;                                   // T *= (1 - alpha)
    }

    if (seg) part[seg - 1][p] = make_float4(r, gc, bc, T);
    __syncthreads();

    if (seg == 0) {
        const float4 s1 = part[0][p];
        const float4 s2 = part[1][p];
        const float4 s3 = part[2][p];
        float cr = fmaf(s2.w, s3.x, s2.x);
        float cg = fmaf(s2.w, s3.y, s2.y);
        float cb = fmaf(s2.w, s3.z, s2.z);
        cr = fmaf(s1.w, cr, s1.x);
        cg = fmaf(s1.w, cg, s1.y);
        cb = fmaf(s1.w, cb, s1.z);
        out[3 * pid]     = fmaf(T, cr, r);
        out[3 * pid + 1] = fmaf(T, cg, gc);
        out[3 * pid + 2] = fmaf(T, cb, bc);
    }
}

extern "C" void kernel_launch(void* const* d_in, const int* in_sizes, int n_in,
                              void* d_out, int out_size, void* d_ws, size_t ws_size,
                              hipStream_t stream) {
    const float* means3d = (const float*)d_in[0];
    const float* scales  = (const float*)d_in[1];
    const float* opac    = (const float*)d_in[2];
    const float* colors  = (const float*)d_in[3];
    float* out = (float*)d_out;

    fused_kernel<<<IMG_H, 1024, 0, stream>>>(means3d, scales, opac, colors, out);
}

// Round 5
// 21.279 us; speedup vs baseline: 2.2906x; 1.1227x over previous
//
#include <hip/hip_runtime.h>

#define IMG_W 256
#define IMG_H 256
#define NG 512
#define NSEG 4
#define SEGLEN (NG / NSEG)   // 128
#define PXB 256              // pixels per block (one image row)
#define FOCAL 50.0f

// Single fused kernel. One block per image row, 1024 threads.
// Phase 1: block-local stable depth sort (u64 keys, split rank count) +
//   per-ROW folding: c = dv^2 * b + log2(opac) is constant across the row.
// Phase 2: 256 px x 4 depth-segments; 8 VALU + 1 exp per pair.
__global__ __launch_bounds__(1024, 1) void fused_kernel(
    const float* __restrict__ means3d, const float* __restrict__ scales,
    const float* __restrict__ opac, const float* __restrict__ colors,
    float* __restrict__ out)
{
    __shared__ __align__(16) unsigned long long zkey[NG];  // 4 KB
    __shared__ int rpart[NG];                    // 2 KB upper-half partial ranks
    __shared__ float4 ga[NG];                    // pu, a, c_row, cr   (8 KB)
    __shared__ float2 gb[NG];                    // cg, cb             (4 KB)
    __shared__ float4 part[NSEG - 1][PXB];       // 12 KB segment partials

    const int tid = threadIdx.x;
    const int i = tid & (NG - 1);                // gaussian id for prep (both halves)

    // ---- phase 1: keys ----
    float z = 0.0f, mx = 0.0f, my = 0.0f;
    if (tid < NG) {
        mx = means3d[3 * i];
        my = means3d[3 * i + 1];
        z  = fmaxf(means3d[3 * i + 2], 0.1f);
        zkey[i] = ((unsigned long long)__float_as_uint(z) << 32) | (unsigned)i;
    }
    __syncthreads();

    // ---- phase 1: split rank count (thread i counts keys [0,256), i+512 counts [256,512)) ----
    const unsigned long long mykey = zkey[i];    // from LDS: valid for both halves
    int cnt = 0;
    {
        const ulonglong2* kp = (const ulonglong2*)zkey + ((tid >> 9) * (NG / 4));
        #pragma unroll 8
        for (int jj = 0; jj < NG / 4; ++jj) {    // 128 iters, 2 keys per b128 broadcast read
            const ulonglong2 kk = kp[jj];
            cnt += (kk.x < mykey);
            cnt += (kk.y < mykey);
        }
    }
    if (tid >= NG) rpart[i] = cnt;               // upper half publishes its partial
    __syncthreads();

    if (tid < NG) {
        const float inv_z = 1.0f / z;
        const float pu = FOCAL * mx * inv_z;
        const float pv = FOCAL * my * inv_z;
        const float su = fmaxf(FOCAL * scales[3 * i] * inv_z, 0.5f);
        const float sv = fmaxf(FOCAL * scales[3 * i + 1] * inv_z, 0.5f);
        const float k = -0.5f * 1.44269504088896340736f;  // -log2(e)/2
        const float a = k / (su * su);
        const float b = k / (sv * sv);
        const float lop = __log2f(opac[i]);
        // per-row fold: dv constant for this block's row
        const float dv = (float)blockIdx.x - (float)(IMG_H / 2) - pv;
        const float c = fmaf(dv * dv, b, lop);
        const int rank = cnt + rpart[i];         // unique: keys are distinct
        ga[rank] = make_float4(pu, a, c, colors[3 * i]);
        gb[rank] = make_float2(colors[3 * i + 1], colors[3 * i + 2]);
    }
    __syncthreads();

    // ---- phase 2: raster ----
    const int p   = tid & (PXB - 1);
    const int seg = tid >> 8;
    const int pid = blockIdx.x * PXB + p;
    const float u = (float)p - (float)(IMG_W / 2);

    float T = 1.0f;
    float r = 0.0f, gc = 0.0f, bc = 0.0f;

    const int base = seg * SEGLEN;
    #pragma unroll 8
    for (int n = 0; n < SEGLEN; ++n) {
        const float4 pa = ga[base + n];          // uniform broadcast reads
        const float2 pb = gb[base + n];
        const float du = u - pa.x;
        const float e = fmaf(du * du, pa.y, pa.z);       // a*du^2 + (b*dv^2 + log2(opac))
        const float alpha = __builtin_amdgcn_exp2f(e);   // v_exp_f32; alpha <= opac < 1
        const float w = alpha * T;
        r  = fmaf(w, pa.w, r);
        gc = fmaf(w, pb.x, gc);
        bc = fmaf(w, pb.y, bc);
        T -= w;                                   // T *= (1 - alpha)
    }

    if (seg) part[seg - 1][p] = make_float4(r, gc, bc, T);
    __syncthreads();

    if (seg == 0) {
        const float4 s1 = part[0][p];
        const float4 s2 = part[1][p];
        const float4 s3 = part[2][p];
        float cr = fmaf(s2.w, s3.x, s2.x);
        float cg = fmaf(s2.w, s3.y, s2.y);
        float cb = fmaf(s2.w, s3.z, s2.z);
        cr = fmaf(s1.w, cr, s1.x);
        cg = fmaf(s1.w, cg, s1.y);
        cb = fmaf(s1.w, cb, s1.z);
        out[3 * pid]     = fmaf(T, cr, r);
        out[3 * pid + 1] = fmaf(T, cg, gc);
        out[3 * pid + 2] = fmaf(T, cb, bc);
    }
}

extern "C" void kernel_launch(void* const* d_in, const int* in_sizes, int n_in,
                              void* d_out, int out_size, void* d_ws, size_t ws_size,
                              hipStream_t stream) {
    const float* means3d = (const float*)d_in[0];
    const float* scales  = (const float*)d_in[1];
    const float* opac    = (const float*)d_in[2];
    const float* colors  = (const float*)d_in[3];
    float* out = (float*)d_out;

    fused_kernel<<<IMG_H, 1024, 0, stream>>>(means3d, scales, opac, colors, out);
}

// Round 6
// 21.141 us; speedup vs baseline: 2.3056x; 1.0065x over previous
//
#include <hip/hip_runtime.h>

#define IMG_W 256
#define IMG_H 256
#define NG 512
#define NSEG 16
#define SEGLEN (NG / NSEG)   // 32
#define PXT 64               // u-threads per block
#define PPT 4                // pixels per thread: u, u+64, u+128, u+192
#define FOCAL 50.0f

// One block per image row, 1024 threads = 64 u-threads x 16 depth-segments,
// 4 pixels per thread (shares the 2 broadcast LDS reads across 4 pixels).
// Phase 1: block-local stable depth sort (u64 keys, split rank count) +
//   per-row folding: c = dv^2 * b + log2(opac).
// Phase 2: composite SEGLEN gaussians per thread; combine 16 segments via LDS.
__global__ __launch_bounds__(1024, 1) void fused_kernel(
    const float* __restrict__ means3d, const float* __restrict__ scales,
    const float* __restrict__ opac, const float* __restrict__ colors,
    float* __restrict__ out)
{
    __shared__ __align__(16) unsigned long long zkey[NG];  // 4 KB
    __shared__ int rpart[NG];                    // 2 KB upper-half partial ranks
    __shared__ float4 ga[NG];                    // pu, a, c_row, cr   (8 KB)
    __shared__ float2 gb[NG];                    // cg, cb             (4 KB)
    __shared__ float4 part[NSEG - 1][PXT][PPT];  // 60 KB segment partials

    const int tid = threadIdx.x;
    const int i = tid & (NG - 1);                // gaussian id for prep (both halves)

    // ---- phase 1: keys ----
    float z = 0.0f, mx = 0.0f, my = 0.0f;
    if (tid < NG) {
        mx = means3d[3 * i];
        my = means3d[3 * i + 1];
        z  = fmaxf(means3d[3 * i + 2], 0.1f);
        zkey[i] = ((unsigned long long)__float_as_uint(z) << 32) | (unsigned)i;
    }
    __syncthreads();

    // ---- phase 1: split rank count (thread i counts keys [0,256), i+512 counts [256,512)) ----
    const unsigned long long mykey = zkey[i];    // from LDS: valid for both halves
    int cnt = 0;
    {
        const ulonglong2* kp = (const ulonglong2*)zkey + ((tid >> 9) * (NG / 4));
        #pragma unroll 8
        for (int jj = 0; jj < NG / 4; ++jj) {    // 128 iters, 2 keys per b128 broadcast read
            const ulonglong2 kk = kp[jj];
            cnt += (kk.x < mykey);
            cnt += (kk.y < mykey);
        }
    }
    if (tid >= NG) rpart[i] = cnt;               // upper half publishes its partial
    __syncthreads();

    if (tid < NG) {
        const float inv_z = 1.0f / z;
        const float pu = FOCAL * mx * inv_z;
        const float pv = FOCAL * my * inv_z;
        const float su = fmaxf(FOCAL * scales[3 * i] * inv_z, 0.5f);
        const float sv = fmaxf(FOCAL * scales[3 * i + 1] * inv_z, 0.5f);
        const float k = -0.5f * 1.44269504088896340736f;  // -log2(e)/2
        const float a = k / (su * su);
        const float b = k / (sv * sv);
        const float lop = __log2f(opac[i]);
        // per-row fold: dv constant for this block's row
        const float dv = (float)blockIdx.x - (float)(IMG_H / 2) - pv;
        const float c = fmaf(dv * dv, b, lop);
        const int rank = cnt + rpart[i];         // unique: keys are distinct
        ga[rank] = make_float4(pu, a, c, colors[3 * i]);
        gb[rank] = make_float2(colors[3 * i + 1], colors[3 * i + 2]);
    }
    __syncthreads();

    // ---- phase 2: raster, 4 px/thread ----
    const int p   = tid & (PXT - 1);
    const int seg = tid >> 6;                    // 0..15

    float u[PPT];
    #pragma unroll
    for (int j = 0; j < PPT; ++j) u[j] = (float)(p + PXT * j) - (float)(IMG_W / 2);

    float T[PPT], ar[PPT], ag[PPT], ab[PPT];
    #pragma unroll
    for (int j = 0; j < PPT; ++j) { T[j] = 1.0f; ar[j] = 0.0f; ag[j] = 0.0f; ab[j] = 0.0f; }

    const int base = seg * SEGLEN;
    #pragma unroll 4
    for (int n = 0; n < SEGLEN; ++n) {
        const float4 pa = ga[base + n];          // uniform broadcast reads
        const float2 pb = gb[base + n];
        #pragma unroll
        for (int j = 0; j < PPT; ++j) {
            const float du = u[j] - pa.x;        // bit-identical to per-pixel reference
            const float e = fmaf(du * du, pa.y, pa.z);       // a*du^2 + (b*dv^2 + log2(opac))
            const float al = __builtin_amdgcn_exp2f(e);      // v_exp_f32
            const float w = al * T[j];
            ar[j] = fmaf(w, pa.w, ar[j]);
            ag[j] = fmaf(w, pb.x, ag[j]);
            ab[j] = fmaf(w, pb.y, ab[j]);
            T[j] -= w;                           // T *= (1 - alpha)
        }
    }

    if (seg) {
        #pragma unroll
        for (int j = 0; j < PPT; ++j)
            part[seg - 1][p][j] = make_float4(ar[j], ag[j], ab[j], T[j]);
    }
    __syncthreads();

    if (seg == 0) {
        for (int s = 1; s < NSEG; ++s) {         // front-to-back segment composition
            #pragma unroll
            for (int j = 0; j < PPT; ++j) {
                const float4 q = part[s - 1][p][j];
                ar[j] = fmaf(T[j], q.x, ar[j]);
                ag[j] = fmaf(T[j], q.y, ag[j]);
                ab[j] = fmaf(T[j], q.z, ab[j]);
                T[j] *= q.w;
            }
        }
        const int row = blockIdx.x;
        #pragma unroll
        for (int j = 0; j < PPT; ++j) {
            const int pid = row * IMG_W + p + PXT * j;
            out[3 * pid]     = ar[j];
            out[3 * pid + 1] = ag[j];
            out[3 * pid + 2] = ab[j];
        }
    }
}

extern "C" void kernel_launch(void* const* d_in, const int* in_sizes, int n_in,
                              void* d_out, int out_size, void* d_ws, size_t ws_size,
                              hipStream_t stream) {
    const float* means3d = (const float*)d_in[0];
    const float* scales  = (const float*)d_in[1];
    const float* opac    = (const float*)d_in[2];
    const float* colors  = (const float*)d_in[3];
    float* out = (float*)d_out;

    fused_kernel<<<IMG_H, 1024, 0, stream>>>(means3d, scales, opac, colors, out);
}

// Round 7
// 20.756 us; speedup vs baseline: 2.3483x; 1.0185x over previous
//
#include <hip/hip_runtime.h>

#define IMG_W 256
#define IMG_H 256
#define NG 512
#define NSEG 16
#define SEGLEN (NG / NSEG)   // 32
#define PXT 64               // u-threads per block
#define PPT 4                // pixels per thread: u, u+64, u+128, u+192
#define FOCAL 50.0f

// One block per image row, 1024 threads = 64 u-threads x 16 depth-segments,
// 4 pixels per thread. Phase 1: block-local stable depth sort (u64 keys,
// split rank count) + per-row folding c = b*dv^2 + log2(opac) + per-row
// cull interval [lo,hi] (u-range where e >= -32; empty if row missed).
// Phase 2: composite with wave-uniform skip of dead gaussians.
__global__ __launch_bounds__(1024, 1) void fused_kernel(
    const float* __restrict__ means3d, const float* __restrict__ scales,
    const float* __restrict__ opac, const float* __restrict__ colors,
    float* __restrict__ out)
{
    __shared__ __align__(16) unsigned long long zkey[NG];  // 4 KB
    __shared__ int rpart[NG];                    // 2 KB upper-half partial ranks
    __shared__ float4 g0[NG];                    // lo, hi, pu, a      (8 KB)
    __shared__ float4 g1[NG];                    // c, cr, cg, cb      (8 KB)
    __shared__ float4 part[NSEG][PPT][PXT];      // 64 KB segment partials

    const int tid = threadIdx.x;
    const int i = tid & (NG - 1);                // gaussian id for prep (both halves)

    // ---- phase 1: keys ----
    float z = 0.0f, mx = 0.0f, my = 0.0f;
    if (tid < NG) {
        mx = means3d[3 * i];
        my = means3d[3 * i + 1];
        z  = fmaxf(means3d[3 * i + 2], 0.1f);
        zkey[i] = ((unsigned long long)__float_as_uint(z) << 32) | (unsigned)i;
    }
    __syncthreads();

    // ---- phase 1: split rank count (thread i counts keys [0,256), i+512 counts [256,512)) ----
    const unsigned long long mykey = zkey[i];    // from LDS: valid for both halves
    int cnt = 0;
    {
        const ulonglong2* kp = (const ulonglong2*)zkey + ((tid >> 9) * (NG / 4));
        #pragma unroll 8
        for (int jj = 0; jj < NG / 4; ++jj) {    // 128 iters, 2 keys per b128 broadcast read
            const ulonglong2 kk = kp[jj];
            cnt += (kk.x < mykey);
            cnt += (kk.y < mykey);
        }
    }
    if (tid >= NG) rpart[i] = cnt;               // upper half publishes its partial
    __syncthreads();

    if (tid < NG) {
        const float inv_z = 1.0f / z;
        const float pu = FOCAL * mx * inv_z;
        const float pv = FOCAL * my * inv_z;
        const float su = fmaxf(FOCAL * scales[3 * i] * inv_z, 0.5f);
        const float sv = fmaxf(FOCAL * scales[3 * i + 1] * inv_z, 0.5f);
        const float k = -0.5f * 1.44269504088896340736f;  // -log2(e)/2
        const float a = k / (su * su);
        const float b = k / (sv * sv);
        const float lop = __log2f(opac[i]);
        // per-row fold: dv constant for this block's row
        const float dv = (float)blockIdx.x - (float)(IMG_H / 2) - pv;
        const float c = fmaf(dv * dv, b, lop);
        // cull interval: e = a*du^2 + c >= -32  =>  |du| <= sqrt((c+32)/(-a))
        float lo = 1e9f, hi = 1e9f;              // empty (row missed) by default
        const float r2 = (c + 32.0f) / (-a);     // a < 0 always
        if (r2 > 0.0f) {
            const float R = sqrtf(r2);
            lo = pu - R;
            hi = pu + R;
        }
        const int rank = cnt + rpart[i];         // unique: keys are distinct
        g0[rank] = make_float4(lo, hi, pu, a);
        g1[rank] = make_float4(c, colors[3 * i], colors[3 * i + 1], colors[3 * i + 2]);
    }
    __syncthreads();

    // ---- phase 2: raster, 4 px/thread, wave-uniform cull ----
    const int p   = tid & (PXT - 1);
    const int seg = tid >> 6;                    // 0..15

    float u[PPT];
    #pragma unroll
    for (int j = 0; j < PPT; ++j) u[j] = (float)(p + PXT * j) - (float)(IMG_W / 2);

    float T[PPT], ar[PPT], ag[PPT], ab[PPT];
    #pragma unroll
    for (int j = 0; j < PPT; ++j) { T[j] = 1.0f; ar[j] = 0.0f; ag[j] = 0.0f; ab[j] = 0.0f; }

    const int base = seg * SEGLEN;
    #pragma unroll 4
    for (int n = 0; n < SEGLEN; ++n) {
        const float4 q0 = g0[base + n];          // lo, hi, pu, a (uniform broadcast)
        if (q0.y < -128.0f || q0.x > 127.0f) continue;   // dead for every px of this row
        const float4 q1 = g1[base + n];          // c, cr, cg, cb
        #pragma unroll
        for (int j = 0; j < PPT; ++j) {
            const float du = u[j] - q0.z;
            const float e = fmaf(du * du, q0.w, q1.x);       // a*du^2 + c
            const float al = __builtin_amdgcn_exp2f(e);      // v_exp_f32
            const float w = al * T[j];
            ar[j] = fmaf(w, q1.y, ar[j]);
            ag[j] = fmaf(w, q1.z, ag[j]);
            ab[j] = fmaf(w, q1.w, ab[j]);
            T[j] -= w;                           // T *= (1 - alpha)
        }
    }

    // ---- combine: all segs publish, 4 waves (j-slices) reduce in parallel ----
    #pragma unroll
    for (int j = 0; j < PPT; ++j)
        part[seg][j][p] = make_float4(ar[j], ag[j], ab[j], T[j]);
    __syncthreads();

    if (tid < PPT * PXT) {                       // waves 0..3
        const int w  = tid >> 6;                 // j-slice
        const int pp = tid & (PXT - 1);
        float4 acc = part[0][w][pp];             // front segment
        #pragma unroll
        for (int s = 1; s < NSEG; ++s) {
            const float4 q = part[s][w][pp];     // conflict-free: lane-contiguous 16B
            acc.x = fmaf(acc.w, q.x, acc.x);
            acc.y = fmaf(acc.w, q.y, acc.y);
            acc.z = fmaf(acc.w, q.z, acc.z);
            acc.w *= q.w;
        }
        const int pid = blockIdx.x * IMG_W + (w * PXT + pp);
        out[3 * pid]     = acc.x;
        out[3 * pid + 1] = acc.y;
        out[3 * pid + 2] = acc.z;
    }
}

extern "C" void kernel_launch(void* const* d_in, const int* in_sizes, int n_in,
                              void* d_out, int out_size, void* d_ws, size_t ws_size,
                              hipStream_t stream) {
    const float* means3d = (const float*)d_in[0];
    const float* scales  = (const float*)d_in[1];
    const float* opac    = (const float*)d_in[2];
    const float* colors  = (const float*)d_in[3];
    float* out = (float*)d_out;

    fused_kernel<<<IMG_H, 1024, 0, stream>>>(means3d, scales, opac, colors, out);
}